// Round 15
// baseline (131.514 us; speedup 1.0000x reference)
//
#include <hip/hip_runtime.h>
#include <cmath>

#define B_    32
#define T_    96
#define N_    512
#define F_    8
#define TF_   768
#define HID_  512
#define M_    16384
#define KIN_  1024
#define KS_   8        // K-split for kan

typedef short short8 __attribute__((ext_vector_type(8)));
typedef _Float16 halfx8 __attribute__((ext_vector_type(8)));
typedef float f32x4  __attribute__((ext_vector_type(4)));
typedef float f32x2  __attribute__((ext_vector_type(2)));
typedef unsigned int  uintx4 __attribute__((ext_vector_type(4)));
typedef unsigned long long ulongx2 __attribute__((ext_vector_type(2)));
typedef unsigned short      ushort_t;
typedef unsigned int        uint_t;
typedef unsigned long long  ulong_t;

// workspace byte offsets (base layout <= 63.7 MB; optional xbf1 extends to 88.9 MB)
#define HT_B     0ull                 // bf16 ht[1024][16384]           = 33,554,432
#define WQ_B     33554432ull          // bf16 wq[8][8][4][4][64][8]     =  1,048,576
#define WB_B     34734080ull          // bf16 wb[1024][768]             =  1,572,864
#define SH_B     36306944ull          // xbf0 bf16 (25.2MB) OVERLAPS kanp[8][16384][64] fp16 (16.8MB)
#define KANR_B   61472768ull          // bf16 kanr[16384][64]           =  2,097,152
#define WFQ_B    63569920ull          // bf16 wfq[6][2][2][4][64][8]    =     98,304
#define XBF2_B   63668224ull          // OPTIONAL bf16 xbf1[16384][768] = 25,165,824 (if ws allows)

// silu(x) ~= sum_k KC[k]*B_k(x) on (-1,1): quasi-interpolant at basis centers
__device__ __constant__ float KC[8] = {
    -0.2818252f, -0.2770046f, -0.2237417f, -0.1031025f,
     0.0968975f,  0.3762583f,  0.7229954f,  1.1181747f };

static __device__ inline uint_t  fbits(float f){ return __builtin_bit_cast(uint_t, f); }
static __device__ inline ushort_t f2b(float f){
    uint_t u = fbits(f);
    return (ushort_t)((u + 0x7fffu + ((u >> 16) & 1u)) >> 16);
}
static __device__ inline float b2f(ushort_t h){ return __builtin_bit_cast(float, (uint_t)h << 16); }
static __device__ inline ulong_t pack4(float4 v){      // RNE
    return (ulong_t)f2b(v.x) | ((ulong_t)f2b(v.y) << 16) |
           ((ulong_t)f2b(v.z) << 32) | ((ulong_t)f2b(v.w) << 48);
}
static __device__ inline ulong_t pack4t(float4 v){     // truncation (cheap)
    uint_t d0 = (fbits(v.x) >> 16) | (fbits(v.y) & 0xffff0000u);
    uint_t d1 = (fbits(v.z) >> 16) | (fbits(v.w) & 0xffff0000u);
    return (ulong_t)d0 | ((ulong_t)d1 << 32);
}
static __device__ inline float fast_tanh(float x){
    const float e = __expf(2.0f * x);
    return 1.0f - 2.0f / (e + 1.0f);
}
static __device__ inline void gload_lds16(const void* g, void* l){
    __builtin_amdgcn_global_load_lds(
        (const __attribute__((address_space(1))) unsigned int*)g,
        (__attribute__((address_space(3))) unsigned int*)l, 16, 0, 0);
}

// ---------------------------------------------------------------------------
// pack_wq: FOLDED KAN weights (spline + silu-as-spline), frag order, KS=8.
// ---------------------------------------------------------------------------
__global__ __launch_bounds__(256) void pack_wq(
    const float* __restrict__ base_w,
    const float* __restrict__ spline_w,
    const float* __restrict__ scaler,
    ushort_t* __restrict__ wq)
{
    const int e = blockIdx.x * 256 + threadIdx.x;   // 524288
    const int j  = e & 7;
    const int ln = (e >> 3) & 63;
    const int ct = (e >> 9) & 3;
    const int t  = (e >> 11) & 3;
    const int ss = (e >> 13) & 7;
    const int ks = e >> 16;
    const int o = ct * 16 + (ln & 15);
    const int g = ln >> 4;
    const int i = ks * 128 + ss * 16 + t * 4 + g;
    const float v = spline_w[(o * KIN_ + i) * 8 + j] * scaler[o * KIN_ + i]
                  + base_w[o * KIN_ + i] * KC[j];
    wq[e] = f2b(v);
}

// ---------------------------------------------------------------------------
// pack_wb2: wb[1024][768] bf16 (rows 0..511 Wx, 512..1023 Wy)
// ---------------------------------------------------------------------------
__global__ __launch_bounds__(256) void pack_wb2(
    const float* __restrict__ Wx,
    const float* __restrict__ Wy,
    ushort_t* __restrict__ wb)
{
    const int e = blockIdx.x * 256 + threadIdx.x;   // 786432
    const float v = (e < 512 * TF_) ? Wx[e] : Wy[e - 512 * TF_];
    wb[e] = f2b(v);
}

// ---------------------------------------------------------------------------
// pack_wfq: Wf frag order, bf16.
// ---------------------------------------------------------------------------
__global__ __launch_bounds__(256) void pack_wfq(
    const float* __restrict__ Wf, ushort_t* __restrict__ wfq)
{
    const int e = blockIdx.x * 256 + threadIdx.x;   // 49152
    const int jj  = e & 7;
    const int ln  = (e >> 3) & 63;
    const int rt  = (e >> 9) & 3;
    const int s   = (e >> 11) & 1;
    const int wvt = (e >> 12) & 1;
    const int tb  = e >> 13;         // 0..5
    const int tf = tb * 128 + wvt * 64 + rt * 16 + (ln & 15);
    const int o  = s * 32 + (ln >> 4) * 8 + jj;
    wfq[e] = f2b(Wf[(size_t)tf * 64 + o]);
}

// ---------------------------------------------------------------------------
// xcvt: xbf[m][k] bf16  <-  Xs[b][t][n][f] fp32  (unchanged)
// ---------------------------------------------------------------------------
__global__ __launch_bounds__(256) void xcvt_kernel(
    const float* __restrict__ Xs, ushort_t* __restrict__ xbf)
{
    __shared__ __align__(16) char lds[32 * 1552];
    const int tid = threadIdx.x;
    const int n0  = blockIdx.x * 32;
    const int bb  = blockIdx.y;
    const int nl  = (tid & 63) >> 1;
    const int f4  = (tid & 1) * 4;
    const int tq  = tid >> 6;
    #pragma unroll 4
    for (int u = 0; u < 24; u++) {
        const int t = u * 4 + tq;
        const float4 v = *(const float4*)(Xs + (size_t)bb * (T_ * N_ * F_)
                                             + (size_t)t * (N_ * F_)
                                             + (size_t)(n0 + nl) * F_ + f4);
        *(ulong_t*)(lds + nl * 1552 + t * 16 + f4 * 2) = pack4t(v);
    }
    __syncthreads();
    #pragma unroll 4
    for (int u = 0; u < 12; u++) {
        const int c   = u * 256 + tid;      // 0..3071
        const int row = c / 96;
        const int col = c - row * 96;
        const uintx4 val = *(const uintx4*)(lds + row * 1552 + col * 16);
        *(uintx4*)(xbf + (size_t)(bb * 512 + n0 + row) * TF_ + col * 8) = val;
    }
}

// ---------------------------------------------------------------------------
// gemm_tanh_v9: v7 internals; grid reordered j-fast (x = j-block, y = m-block)
// so the 4 j-blocks sharing an A panel dispatch adjacently (L2/L3 reuse);
// optional z-merge (blockIdx.z + zbase) runs X and Y halves in one launch.
// ---------------------------------------------------------------------------
__global__ __launch_bounds__(512, 2) void gemm_tanh_v9(
    const ushort_t* __restrict__ xbf0,
    const ushort_t* __restrict__ xbf1,
    const ushort_t* __restrict__ wb,
    const float* __restrict__ bx, const float* __restrict__ by,
    ushort_t* __restrict__ ht, int zbase)
{
    __shared__ __align__(16) char smem[32768];

    const int z = zbase + blockIdx.z;
    const ushort_t* xbf = z ? xbf1 : xbf0;
    const float* bias   = z ? by : bx;

    const int tid = threadIdx.x;
    const int wv  = tid >> 6;          // 0..7
    const int ln  = tid & 63;
    const int lr  = ln & 15;
    const int hi  = ln >> 4;
    const int wm  = wv >> 2;           // m-half
    const int wj  = wv & 3;            // j-quarter (32 cols)

    const int jl0 = blockIdx.x * 128;  // j fast-varying across block ids
    const int m0  = blockIdx.y * 128;
    const int j0  = z * 512 + jl0;

    const int r_l = ln >> 3;                    // row within 8-row region
    const int ck  = ((ln & 7) ^ r_l) * 8;       // inverse-swizzled src chunk

    f32x4 acc[4][2] = {};

    for (int kt = 0; kt < 12; kt++) {
        __syncthreads();
        #pragma unroll
        for (int s = 0; s < 2; s++) {
            const int reg = s * 8 + wv;          // 0..15
            const int row = reg * 8 + r_l;
            gload_lds16(xbf + (size_t)(m0 + row) * TF_ + kt * 64 + ck,
                        smem + reg * 1024 + ln * 16);
            gload_lds16(wb + (size_t)(j0 + row) * TF_ + kt * 64 + ck,
                        smem + 16384 + reg * 1024 + ln * 16);
        }
        __syncthreads();

        #pragma unroll
        for (int h = 0; h < 2; h++) {
            const int g = h * 4 + hi;
            short8 a[4], b[2];
            #pragma unroll
            for (int rt = 0; rt < 4; rt++) {
                const int r = wm * 64 + rt * 16 + lr;
                a[rt] = *(short8*)(smem + r * 128 + ((g ^ (r & 7)) * 16));
            }
            #pragma unroll
            for (int ct = 0; ct < 2; ct++) {
                const int r = wj * 32 + ct * 16 + lr;
                b[ct] = *(short8*)(smem + 16384 + r * 128 + ((g ^ (r & 7)) * 16));
            }
            #pragma unroll
            for (int rt = 0; rt < 4; rt++)
                #pragma unroll
                for (int ct = 0; ct < 2; ct++)
                    acc[rt][ct] = __builtin_amdgcn_mfma_f32_16x16x32_bf16(
                        a[rt], b[ct], acc[rt][ct], 0, 0, 0);
        }
    }

    // epilogue: tanh -> bf16 LDS [j 128][m 128] (16B-slot ^ (j&15)) -> ht
    __syncthreads();
    #pragma unroll
    for (int ct = 0; ct < 2; ct++) {
        const int j = wj * 32 + ct * 16 + lr;
        const float bvv = bias[jl0 + j];
        #pragma unroll
        for (int rt = 0; rt < 4; rt++) {
            const f32x4 v = acc[rt][ct];
            float4 tv;
            tv.x = fast_tanh(v[0] + bvv);
            tv.y = fast_tanh(v[1] + bvv);
            tv.z = fast_tanh(v[2] + bvv);
            tv.w = fast_tanh(v[3] + bvv);
            const int slot = wm * 8 + rt * 2 + (hi >> 1);
            *(ulong_t*)(smem + j * 256 + ((slot ^ (j & 15)) * 16) + (hi & 1) * 8)
                = pack4(tv);
        }
    }
    __syncthreads();
    {
        const int j  = tid >> 2;             // 0..127
        const int q4 = tid & 3;
        ushort_t* dst = ht + (size_t)(j0 + j) * M_ + m0 + q4 * 32;
        #pragma unroll
        for (int w = 0; w < 4; w++) {
            const int slot = q4 * 4 + w;
            short8 val = *(short8*)(smem + j * 256 + ((slot ^ (j & 15)) * 16));
            *(short8*)(dst + w * 8) = val;
        }
    }
}

// ---------------------------------------------------------------------------
// kan_v10b (unchanged from round 14; proven).
// ---------------------------------------------------------------------------
static __device__ inline short8 shift_pack(float b0, float b1, float b2, float b3, int si)
{
    const uint_t d0 = (fbits(b0) >> 16) | (fbits(b1) & 0xffff0000u);
    const uint_t d1 = (fbits(b2) >> 16) | (fbits(b3) & 0xffff0000u);
    const ulong_t P = (ulong_t)d0 | ((ulong_t)d1 << 32);
    const int sh = si << 4;
    const ulong_t Plo = P << (sh & 63);
    const ulong_t Phi = P >> ((64 - sh) & 63);
    ulongx2 pr;
    pr.x = (si == 4) ? 0ull : Plo;
    pr.y = (si == 0) ? 0ull : ((si == 4) ? P : Phi);
    return __builtin_bit_cast(short8, pr);
}

static __device__ inline void eval_bases2(float x0, float x1, short8& a0, short8& a1)
{
    f32x2 x = {x0, x1};
    f32x2 v = x * 2.5f + 2.5f;
    f32x2 sf = __builtin_elementwise_floor(v);
    sf = __builtin_elementwise_min(sf, (f32x2){4.0f, 4.0f});
    const f32x2 u  = v - sf;
    const f32x2 u2 = u * u;
    const f32x2 u3 = u2 * u;
    const f32x2 omu = 1.0f - u;
    const f32x2 omu3 = omu * omu * omu;
    const f32x2 B0 = omu3 * (1.0f / 6.0f);
    const f32x2 B3 = u3 * (1.0f / 6.0f);
    const f32x2 B1 = (u3 * 0.5f + (2.0f / 3.0f)) - u2;
    const f32x2 B2 = 1.0f - B0 - B1 - B3;
    a0 = shift_pack(B0[0], B1[0], B2[0], B3[0], (int)sf[0]);
    a1 = shift_pack(B0[1], B1[1], B2[1], B3[1], (int)sf[1]);
}

__global__ __launch_bounds__(256) void kan_v10b(
    const ushort_t* __restrict__ ht,
    const ushort_t* __restrict__ wq,
    _Float16* __restrict__ kanp)
{
    __shared__ __align__(16) char lds[49152];   // hts 32K (swizzled) + 2x8K wbuf

    const int tid = threadIdx.x;
    const int wv  = tid >> 6;
    const int ln  = tid & 63;
    const int g   = ln >> 4;
    const int lr  = ln & 15;
    const int m0  = blockIdx.x * 128;
    const int ks  = blockIdx.y;
    const int iB  = ks * 128;

    const ushort_t* wqk = wq + (size_t)ks * 65536;

    #pragma unroll
    for (int c = 0; c < 8; c++) {
        const int ll = wv * 8 + c;                   // 0..31
        const int il = ll * 4 + (ln >> 4);           // 0..127
        const int chunk = ln & 15;
        const int rowst = (chunk ^ ((il & 3) << 1)) * 8;   // inverse swizzle
        gload_lds16(ht + (size_t)(iB + il) * M_ + m0 + rowst,
                    lds + ll * 1024 + (ln & 15) * 16 + (ln >> 4) * 256);
    }
    gload_lds16(wqk + (size_t)wv * 512 + ln * 8,
                lds + 32768 + wv * 1024 + ln * 16);
    gload_lds16(wqk + (size_t)(4 + wv) * 512 + ln * 8,
                lds + 32768 + (4 + wv) * 1024 + ln * 16);
    short8 wA0 = *(const short8*)(wqk + (size_t)(8 + wv) * 512 + ln * 8);
    short8 wA1 = *(const short8*)(wqk + (size_t)(12 + wv) * 512 + ln * 8);
    short8 wB0 = *(const short8*)(wqk + (size_t)(16 + wv) * 512 + ln * 8);
    short8 wB1 = *(const short8*)(wqk + (size_t)(20 + wv) * 512 + ln * 8);
    __syncthreads();

    const int hb0 = g * 256 + ((wv * 64 + lr * 2) ^ (g << 5));
    const int hb1 = g * 256 + ((wv * 64 + 32 + lr * 2) ^ (g << 5));

    f32x4 acc[2][4] = {};

    #pragma unroll 4
    for (int p = 0; p < 16; ++p) {
        char* rb = lds + 32768 + (p & 1) * 8192;
        short8 bfr[8];
        #pragma unroll
        for (int f = 0; f < 8; f++)
            bfr[f] = *(short8*)(rb + f * 1024 + ln * 16);

        if (p < 15) {
            char* wbuf = lds + 32768 + ((p + 1) & 1) * 8192;
            *(short8*)(wbuf + wv * 1024 + ln * 16)       = wA0;
            *(short8*)(wbuf + (4 + wv) * 1024 + ln * 16) = wA1;
        }
        wA0 = wB0; wA1 = wB1;
        if (p < 13) {
            wB0 = *(const short8*)(wqk + (size_t)((p + 3) * 8 + wv) * 512 + ln * 8);
            wB1 = *(const short8*)(wqk + (size_t)((p + 3) * 8 + 4 + wv) * 512 + ln * 8);
        }

        const int itA = 2 * p, itB = 2 * p + 1;
        short8 a0, a1, a2, a3;
        eval_bases2(b2f(*(const ushort_t*)(lds + hb0 + itA * 1024)),
                    b2f(*(const ushort_t*)(lds + hb1 + itA * 1024)), a0, a1);
        eval_bases2(b2f(*(const ushort_t*)(lds + hb0 + itB * 1024)),
                    b2f(*(const ushort_t*)(lds + hb1 + itB * 1024)), a2, a3);

        acc[0][0] = __builtin_amdgcn_mfma_f32_16x16x32_bf16(a0, bfr[0], acc[0][0], 0, 0, 0);
        acc[0][1] = __builtin_amdgcn_mfma_f32_16x16x32_bf16(a0, bfr[1], acc[0][1], 0, 0, 0);
        acc[0][2] = __builtin_amdgcn_mfma_f32_16x16x32_bf16(a0, bfr[2], acc[0][2], 0, 0, 0);
        acc[0][3] = __builtin_amdgcn_mfma_f32_16x16x32_bf16(a0, bfr[3], acc[0][3], 0, 0, 0);
        acc[1][0] = __builtin_amdgcn_mfma_f32_16x16x32_bf16(a1, bfr[0], acc[1][0], 0, 0, 0);
        acc[1][1] = __builtin_amdgcn_mfma_f32_16x16x32_bf16(a1, bfr[1], acc[1][1], 0, 0, 0);
        acc[1][2] = __builtin_amdgcn_mfma_f32_16x16x32_bf16(a1, bfr[2], acc[1][2], 0, 0, 0);
        acc[1][3] = __builtin_amdgcn_mfma_f32_16x16x32_bf16(a1, bfr[3], acc[1][3], 0, 0, 0);
        acc[0][0] = __builtin_amdgcn_mfma_f32_16x16x32_bf16(a2, bfr[4], acc[0][0], 0, 0, 0);
        acc[0][1] = __builtin_amdgcn_mfma_f32_16x16x32_bf16(a2, bfr[5], acc[0][1], 0, 0, 0);
        acc[0][2] = __builtin_amdgcn_mfma_f32_16x16x32_bf16(a2, bfr[6], acc[0][2], 0, 0, 0);
        acc[0][3] = __builtin_amdgcn_mfma_f32_16x16x32_bf16(a2, bfr[7], acc[0][3], 0, 0, 0);
        acc[1][0] = __builtin_amdgcn_mfma_f32_16x16x32_bf16(a3, bfr[4], acc[1][0], 0, 0, 0);
        acc[1][1] = __builtin_amdgcn_mfma_f32_16x16x32_bf16(a3, bfr[5], acc[1][1], 0, 0, 0);
        acc[1][2] = __builtin_amdgcn_mfma_f32_16x16x32_bf16(a3, bfr[6], acc[1][2], 0, 0, 0);
        acc[1][3] = __builtin_amdgcn_mfma_f32_16x16x32_bf16(a3, bfr[7], acc[1][3], 0, 0, 0);

        __syncthreads();
    }

    #pragma unroll
    for (int rt = 0; rt < 2; rt++) {
        #pragma unroll
        for (int ct = 0; ct < 4; ct++) {
            const int o = ct * 16 + lr;
            #pragma unroll
            for (int q = 0; q < 4; q++) {
                const size_t row = (size_t)(m0 + wv * 32 + rt * 16 + g * 4 + q);
                kanp[(size_t)ks * (M_ * 64) + row * 64 + o] = (_Float16)acc[rt][ct][q];
            }
        }
    }
}

// ---------------------------------------------------------------------------
// reduce_kan: kanr[m][o] bf16 = sum_ks kanp_fp16[ks][m][o]
// ---------------------------------------------------------------------------
__global__ __launch_bounds__(256) void reduce_kan(
    const _Float16* __restrict__ kanp, ushort_t* __restrict__ kanr)
{
    const int e8 = blockIdx.x * 256 + threadIdx.x;   // 131072 threads
    const size_t base = (size_t)e8 * 8;
    float s[8] = {};
    #pragma unroll
    for (int p = 0; p < KS_; p++) {
        const halfx8 v = *(const halfx8*)(kanp + (size_t)p * (M_ * 64) + base);
        #pragma unroll
        for (int j = 0; j < 8; j++) s[j] += (float)v[j];
    }
    float4 s0 = make_float4(s[0], s[1], s[2], s[3]);
    float4 s1 = make_float4(s[4], s[5], s[6], s[7]);
    ulongx2 outv;
    outv.x = pack4(s0);
    outv.y = pack4(s1);
    *(ulongx2*)(kanr + base) = outv;
}

// ---------------------------------------------------------------------------
// final_v2: out = kanr @ Wf^T + bf, MFMA, float4 stores.
// ---------------------------------------------------------------------------
__global__ __launch_bounds__(256) void final_v2(
    const ushort_t* __restrict__ kanr,
    const ushort_t* __restrict__ wfq,
    const float* __restrict__ bf,
    float* __restrict__ out)
{
    const int tid = threadIdx.x;
    const int wv  = tid >> 6;
    const int ln  = tid & 63;
    const int lr  = ln & 15;
    const int hi  = ln >> 4;
    const int wvm = wv >> 1;
    const int wvt = wv & 1;
    const int mb  = blockIdx.x;
    const int tb  = blockIdx.y;

    f32x4 acc[4][4] = {};

    #pragma unroll
    for (int s = 0; s < 2; s++) {
        short8 afr[4], bfr[4];
        #pragma unroll
        for (int rt = 0; rt < 4; rt++) {
            const size_t idx = ((size_t)(((tb * 2 + wvt) * 2 + s) * 4 + rt)) * 64 + ln;
            afr[rt] = ((const short8*)wfq)[idx];
        }
        #pragma unroll
        for (int ct = 0; ct < 4; ct++) {
            const int m = mb * 128 + wvm * 64 + ct * 16 + lr;
            bfr[ct] = *(const short8*)(kanr + (size_t)m * 64 + s * 32 + hi * 8);
        }
        #pragma unroll
        for (int rt = 0; rt < 4; rt++)
            #pragma unroll
            for (int ct = 0; ct < 4; ct++)
                acc[rt][ct] = __builtin_amdgcn_mfma_f32_16x16x32_bf16(
                    afr[rt], bfr[ct], acc[rt][ct], 0, 0, 0);
    }

    #pragma unroll
    for (int rt = 0; rt < 4; rt++) {
        const int tf0 = tb * 128 + wvt * 64 + rt * 16 + hi * 4;
        const float4 b4 = *(const float4*)&bf[tf0];
        const int t  = tf0 >> 3;
        const int f0 = tf0 & 7;
        #pragma unroll
        for (int ct = 0; ct < 4; ct++) {
            const int m = mb * 128 + wvm * 64 + ct * 16 + lr;
            const int bb = m >> 9;
            const int n  = m & 511;
            const f32x4 v = acc[rt][ct];
            float4 o4 = make_float4(v[0] + b4.x, v[1] + b4.y, v[2] + b4.z, v[3] + b4.w);
            *(float4*)&out[(size_t)bb * (T_ * N_ * F_)
                           + (size_t)t * (N_ * F_)
                           + (size_t)n * F_ + f0] = o4;
        }
    }
}

// ---------------------------------------------------------------------------
extern "C" void kernel_launch(void* const* d_in, const int* in_sizes, int n_in,
                              void* d_out, int out_size, void* d_ws, size_t ws_size,
                              hipStream_t stream)
{
    const float* X      = (const float*)d_in[0];
    const float* Y      = (const float*)d_in[1];
    const float* Wx     = (const float*)d_in[2];
    const float* bx     = (const float*)d_in[3];
    const float* Wy     = (const float*)d_in[4];
    const float* by     = (const float*)d_in[5];
    const float* base_w = (const float*)d_in[6];
    const float* spline_w = (const float*)d_in[7];
    const float* spline_scaler = (const float*)d_in[8];
    const float* Wf     = (const float*)d_in[9];
    const float* bf     = (const float*)d_in[10];

    float* out = (float*)d_out;
    ushort_t* ht   = (ushort_t*)((char*)d_ws + HT_B);
    ushort_t* wq   = (ushort_t*)((char*)d_ws + WQ_B);
    ushort_t* wb   = (ushort_t*)((char*)d_ws + WB_B);
    ushort_t* xbf0 = (ushort_t*)((char*)d_ws + SH_B);   // overlaps kanp
    _Float16* kanp = (_Float16*)((char*)d_ws + SH_B);
    ushort_t* kanr = (ushort_t*)((char*)d_ws + KANR_B);
    ushort_t* wfq  = (ushort_t*)((char*)d_ws + WFQ_B);

    const bool merged = ws_size >= (size_t)(XBF2_B + 25165824ull);
    ushort_t* xbf1 = merged ? (ushort_t*)((char*)d_ws + XBF2_B) : xbf0;

    pack_wq<<<2048, 256, 0, stream>>>(base_w, spline_w, spline_scaler, wq);
    pack_wb2<<<3072, 256, 0, stream>>>(Wx, Wy, wb);
    pack_wfq<<<192, 256, 0, stream>>>(Wf, wfq);

    if (merged) {
        // both halves converted up front; single z-merged GEMM launch
        xcvt_kernel<<<dim3(16, 32), 256, 0, stream>>>(X, xbf0);
        xcvt_kernel<<<dim3(16, 32), 256, 0, stream>>>(Y, xbf1);
        gemm_tanh_v9<<<dim3(4, 128, 2), 512, 0, stream>>>(
            xbf0, xbf1, wb, bx, by, ht, 0);
    } else {
        // sequential fallback (still j-fast block ordering)
        xcvt_kernel<<<dim3(16, 32), 256, 0, stream>>>(X, xbf0);
        gemm_tanh_v9<<<dim3(4, 128, 1), 512, 0, stream>>>(
            xbf0, xbf0, wb, bx, by, ht, 0);
        xcvt_kernel<<<dim3(16, 32), 256, 0, stream>>>(Y, xbf0);
        gemm_tanh_v9<<<dim3(4, 128, 1), 512, 0, stream>>>(
            xbf0, xbf0, wb, bx, by, ht, 1);
    }

    kan_v10b<<<dim3(M_ / 128, KS_), 256, 0, stream>>>(ht, wq, kanp);
    reduce_kan<<<512, 256, 0, stream>>>(kanp, kanr);
    final_v2<<<dim3(128, 6), 256, 0, stream>>>(kanr, wfq, bf, out);
}

// Round 16
// 131.332 us; speedup vs baseline: 1.0014x; 1.0014x over previous
//
#include <hip/hip_runtime.h>
#include <cmath>

#define B_    32
#define T_    96
#define N_    512
#define F_    8
#define TF_   768
#define HID_  512
#define M_    16384
#define KIN_  1024
#define KS_   8        // K-split for kan

typedef short short8 __attribute__((ext_vector_type(8)));
typedef _Float16 halfx8 __attribute__((ext_vector_type(8)));
typedef float f32x4  __attribute__((ext_vector_type(4)));
typedef float f32x2  __attribute__((ext_vector_type(2)));
typedef unsigned int  uintx4 __attribute__((ext_vector_type(4)));
typedef unsigned long long ulongx2 __attribute__((ext_vector_type(2)));
typedef unsigned short      ushort_t;
typedef unsigned int        uint_t;
typedef unsigned long long  ulong_t;

// workspace byte offsets (total <= 63.7 MB)
#define HT_B     0ull                 // bf16 ht[1024][16384]           = 33,554,432
#define WQ_B     33554432ull          // bf16 wq[8][8][4][4][64][8]     =  1,048,576
#define WB_B     34734080ull          // bf16 wb[1024][768]             =  1,572,864
#define SH_B     36306944ull          // fp16 kanp[8][16384][64]        = 16,777,216
#define KANR_B   61472768ull          // bf16 kanr[16384][64]           =  2,097,152
#define WFQ_B    63569920ull          // bf16 wfq[6][2][2][4][64][8]    =     98,304

// silu(x) ~= sum_k KC[k]*B_k(x) on (-1,1): quasi-interpolant at basis centers
__device__ __constant__ float KC[8] = {
    -0.2818252f, -0.2770046f, -0.2237417f, -0.1031025f,
     0.0968975f,  0.3762583f,  0.7229954f,  1.1181747f };

static __device__ inline uint_t  fbits(float f){ return __builtin_bit_cast(uint_t, f); }
static __device__ inline ushort_t f2b(float f){
    uint_t u = fbits(f);
    return (ushort_t)((u + 0x7fffu + ((u >> 16) & 1u)) >> 16);
}
static __device__ inline float b2f(ushort_t h){ return __builtin_bit_cast(float, (uint_t)h << 16); }
static __device__ inline ulong_t pack4(float4 v){      // RNE
    return (ulong_t)f2b(v.x) | ((ulong_t)f2b(v.y) << 16) |
           ((ulong_t)f2b(v.z) << 32) | ((ulong_t)f2b(v.w) << 48);
}
static __device__ inline ulong_t pack4t(float4 v){     // truncation (cheap; == xcvt)
    uint_t d0 = (fbits(v.x) >> 16) | (fbits(v.y) & 0xffff0000u);
    uint_t d1 = (fbits(v.z) >> 16) | (fbits(v.w) & 0xffff0000u);
    return (ulong_t)d0 | ((ulong_t)d1 << 32);
}
static __device__ inline float fast_tanh(float x){
    const float e = __expf(2.0f * x);
    return 1.0f - 2.0f / (e + 1.0f);
}
static __device__ inline void gload_lds16(const void* g, void* l){
    __builtin_amdgcn_global_load_lds(
        (const __attribute__((address_space(1))) unsigned int*)g,
        (__attribute__((address_space(3))) unsigned int*)l, 16, 0, 0);
}

// ---------------------------------------------------------------------------
// pack_wq: FOLDED KAN weights (spline + silu-as-spline), frag order, KS=8.
// ---------------------------------------------------------------------------
__global__ __launch_bounds__(256) void pack_wq(
    const float* __restrict__ base_w,
    const float* __restrict__ spline_w,
    const float* __restrict__ scaler,
    ushort_t* __restrict__ wq)
{
    const int e = blockIdx.x * 256 + threadIdx.x;   // 524288
    const int j  = e & 7;
    const int ln = (e >> 3) & 63;
    const int ct = (e >> 9) & 3;
    const int t  = (e >> 11) & 3;
    const int ss = (e >> 13) & 7;
    const int ks = e >> 16;
    const int o = ct * 16 + (ln & 15);
    const int g = ln >> 4;
    const int i = ks * 128 + ss * 16 + t * 4 + g;
    const float v = spline_w[(o * KIN_ + i) * 8 + j] * scaler[o * KIN_ + i]
                  + base_w[o * KIN_ + i] * KC[j];
    wq[e] = f2b(v);
}

// ---------------------------------------------------------------------------
// pack_wb2: wb[1024][768] bf16 (rows 0..511 Wx, 512..1023 Wy)
// ---------------------------------------------------------------------------
__global__ __launch_bounds__(256) void pack_wb2(
    const float* __restrict__ Wx,
    const float* __restrict__ Wy,
    ushort_t* __restrict__ wb)
{
    const int e = blockIdx.x * 256 + threadIdx.x;   // 786432
    const float v = (e < 512 * TF_) ? Wx[e] : Wy[e - 512 * TF_];
    wb[e] = f2b(v);
}

// ---------------------------------------------------------------------------
// pack_wfq: Wf frag order, bf16.
// ---------------------------------------------------------------------------
__global__ __launch_bounds__(256) void pack_wfq(
    const float* __restrict__ Wf, ushort_t* __restrict__ wfq)
{
    const int e = blockIdx.x * 256 + threadIdx.x;   // 49152
    const int jj  = e & 7;
    const int ln  = (e >> 3) & 63;
    const int rt  = (e >> 9) & 3;
    const int s   = (e >> 11) & 1;
    const int wvt = (e >> 12) & 1;
    const int tb  = e >> 13;         // 0..5
    const int tf = tb * 128 + wvt * 64 + rt * 16 + (ln & 15);
    const int o  = s * 32 + (ln >> 4) * 8 + jj;
    wfq[e] = f2b(Wf[(size_t)tf * 64 + o]);
}

// ---------------------------------------------------------------------------
// gemm_tanh_v10: direct fp32 gather (no xcvt/xbf) + XCD-aware block decode.
// ht[j0+j][m] = tanh( sum_k Xf[m,k]*wb[j0+j,k] + bias[jl0+j] )
// 1024 blocks 1-D; decode: xcd=bid&7, q=bid>>3, jb=q&3, pi=xcd*32+(q>>2),
// z=pi>>7, mb=pi&127  -> the 4 j-blocks of a (z,mb) pair sit on ONE XCD,
// dispatched within 24 bids of each other (A panel fetched once, L2-shared).
// A: per-kt register gather from X/Y (fp32, coalesced 32B/row segments),
// truncation-pack, swizzled ds_write_b128; prefetched across MFMA phase.
// B: global_load_lds (linear dest, inverse-swizzled source).  BK=64, 8 waves.
// ---------------------------------------------------------------------------
__global__ __launch_bounds__(512, 2) void gemm_tanh_v10(
    const float* __restrict__ X, const float* __restrict__ Y,
    const ushort_t* __restrict__ wb,
    const float* __restrict__ bx, const float* __restrict__ by,
    ushort_t* __restrict__ ht)
{
    __shared__ __align__(16) char smem[32768];   // A:[0,16K) B:[16K,32K)

    const int bid = blockIdx.x;
    const int xcd = bid & 7;
    const int q   = bid >> 3;          // 0..127
    const int jb  = q & 3;
    const int pi  = xcd * 32 + (q >> 2);   // 0..255
    const int z   = pi >> 7;
    const int mb  = pi & 127;

    const float* Xs   = z ? Y : X;
    const float* bias = z ? by : bx;

    const int tid = threadIdx.x;
    const int wv  = tid >> 6;          // 0..7
    const int ln  = tid & 63;
    const int lr  = ln & 15;
    const int hi  = ln >> 4;
    const int wm  = wv >> 2;           // m-half
    const int wj  = wv & 3;            // j-quarter (32 cols)

    const int jl0 = jb * 128;
    const int m0  = mb * 128;
    const int j0  = z * 512 + jl0;
    const int bb  = m0 >> 9;
    const int n0  = m0 & 511;

    // A gather roles: row = tid>>2 (0..127), aq = tid&3 covers k = aq*16..+16
    const int arow = tid >> 2;
    const int aq   = tid & 3;
    const float* abase = Xs + (size_t)bb * (T_ * N_ * F_)
                            + (size_t)(n0 + arow) * F_;

    // B stage roles (proven v9 mapping)
    const int r_l = ln >> 3;
    const int ck  = ((ln & 7) ^ r_l) * 8;

    f32x4 acc[4][2] = {};

    // prologue: A regs for kt=0 (t0 = aq*2)
    float4 pv0, pv1, pv2, pv3;
    {
        const size_t t0 = (size_t)(aq * 2) * (N_ * F_);
        pv0 = *(const float4*)(abase + t0);
        pv1 = *(const float4*)(abase + t0 + 4);
        pv2 = *(const float4*)(abase + t0 + (N_ * F_));
        pv3 = *(const float4*)(abase + t0 + (N_ * F_) + 4);
    }

    for (int kt = 0; kt < 12; kt++) {
        __syncthreads();               // prev compute's LDS reads done
        {   // A: pack + 2 swizzled b128 writes (slots aq*2, aq*2+1)
            ulongx2 w0, w1;
            w0.x = pack4t(pv0); w0.y = pack4t(pv1);
            w1.x = pack4t(pv2); w1.y = pack4t(pv3);
            const int s0 = aq * 2;
            *(ulongx2*)(smem + arow * 128 + ((s0       ^ (arow & 7)) * 16)) = w0;
            *(ulongx2*)(smem + arow * 128 + (((s0 + 1) ^ (arow & 7)) * 16)) = w1;
        }
        // B: 2x global_load_lds per thread (16KB tile)
        #pragma unroll
        for (int s = 0; s < 2; s++) {
            const int reg = s * 8 + wv;          // 0..15
            const int row = reg * 8 + r_l;
            gload_lds16(wb + (size_t)(j0 + row) * TF_ + kt * 64 + ck,
                        smem + 16384 + reg * 1024 + ln * 16);
        }
        __syncthreads();               // A visible + B landed

        // prefetch next kt's A (latency hides under 32 MFMAs)
        if (kt < 11) {
            const size_t t0 = (size_t)((kt + 1) * 8 + aq * 2) * (N_ * F_);
            pv0 = *(const float4*)(abase + t0);
            pv1 = *(const float4*)(abase + t0 + 4);
            pv2 = *(const float4*)(abase + t0 + (N_ * F_));
            pv3 = *(const float4*)(abase + t0 + (N_ * F_) + 4);
        }

        #pragma unroll
        for (int h = 0; h < 2; h++) {
            const int g = h * 4 + hi;
            short8 a[4], b[2];
            #pragma unroll
            for (int rt = 0; rt < 4; rt++) {
                const int r = wm * 64 + rt * 16 + lr;
                a[rt] = *(short8*)(smem + r * 128 + ((g ^ (r & 7)) * 16));
            }
            #pragma unroll
            for (int ct = 0; ct < 2; ct++) {
                const int r = wj * 32 + ct * 16 + lr;
                b[ct] = *(short8*)(smem + 16384 + r * 128 + ((g ^ (r & 7)) * 16));
            }
            #pragma unroll
            for (int rt = 0; rt < 4; rt++)
                #pragma unroll
                for (int ct = 0; ct < 2; ct++)
                    acc[rt][ct] = __builtin_amdgcn_mfma_f32_16x16x32_bf16(
                        a[rt], b[ct], acc[rt][ct], 0, 0, 0);
        }
    }

    // epilogue: tanh -> bf16 LDS [j 128][m 128] (16B-slot ^ (j&15)) -> ht
    __syncthreads();
    #pragma unroll
    for (int ct = 0; ct < 2; ct++) {
        const int j = wj * 32 + ct * 16 + lr;
        const float bvv = bias[jl0 + j];
        #pragma unroll
        for (int rt = 0; rt < 4; rt++) {
            const f32x4 v = acc[rt][ct];
            float4 tv;
            tv.x = fast_tanh(v[0] + bvv);
            tv.y = fast_tanh(v[1] + bvv);
            tv.z = fast_tanh(v[2] + bvv);
            tv.w = fast_tanh(v[3] + bvv);
            const int slot = wm * 8 + rt * 2 + (hi >> 1);
            *(ulong_t*)(smem + j * 256 + ((slot ^ (j & 15)) * 16) + (hi & 1) * 8)
                = pack4(tv);
        }
    }
    __syncthreads();
    {
        const int j  = tid >> 2;             // 0..127
        const int q4 = tid & 3;
        ushort_t* dst = ht + (size_t)(j0 + j) * M_ + m0 + q4 * 32;
        #pragma unroll
        for (int w = 0; w < 4; w++) {
            const int slot = q4 * 4 + w;
            short8 val = *(short8*)(smem + j * 256 + ((slot ^ (j & 15)) * 16));
            *(short8*)(dst + w * 8) = val;
        }
    }
}

// ---------------------------------------------------------------------------
// kan_v10b (unchanged; proven).
// ---------------------------------------------------------------------------
static __device__ inline short8 shift_pack(float b0, float b1, float b2, float b3, int si)
{
    const uint_t d0 = (fbits(b0) >> 16) | (fbits(b1) & 0xffff0000u);
    const uint_t d1 = (fbits(b2) >> 16) | (fbits(b3) & 0xffff0000u);
    const ulong_t P = (ulong_t)d0 | ((ulong_t)d1 << 32);
    const int sh = si << 4;
    const ulong_t Plo = P << (sh & 63);
    const ulong_t Phi = P >> ((64 - sh) & 63);
    ulongx2 pr;
    pr.x = (si == 4) ? 0ull : Plo;
    pr.y = (si == 0) ? 0ull : ((si == 4) ? P : Phi);
    return __builtin_bit_cast(short8, pr);
}

static __device__ inline void eval_bases2(float x0, float x1, short8& a0, short8& a1)
{
    f32x2 x = {x0, x1};
    f32x2 v = x * 2.5f + 2.5f;
    f32x2 sf = __builtin_elementwise_floor(v);
    sf = __builtin_elementwise_min(sf, (f32x2){4.0f, 4.0f});
    const f32x2 u  = v - sf;
    const f32x2 u2 = u * u;
    const f32x2 u3 = u2 * u;
    const f32x2 omu = 1.0f - u;
    const f32x2 omu3 = omu * omu * omu;
    const f32x2 B0 = omu3 * (1.0f / 6.0f);
    const f32x2 B3 = u3 * (1.0f / 6.0f);
    const f32x2 B1 = (u3 * 0.5f + (2.0f / 3.0f)) - u2;
    const f32x2 B2 = 1.0f - B0 - B1 - B3;
    a0 = shift_pack(B0[0], B1[0], B2[0], B3[0], (int)sf[0]);
    a1 = shift_pack(B0[1], B1[1], B2[1], B3[1], (int)sf[1]);
}

__global__ __launch_bounds__(256) void kan_v10b(
    const ushort_t* __restrict__ ht,
    const ushort_t* __restrict__ wq,
    _Float16* __restrict__ kanp)
{
    __shared__ __align__(16) char lds[49152];   // hts 32K (swizzled) + 2x8K wbuf

    const int tid = threadIdx.x;
    const int wv  = tid >> 6;
    const int ln  = tid & 63;
    const int g   = ln >> 4;
    const int lr  = ln & 15;
    const int m0  = blockIdx.x * 128;
    const int ks  = blockIdx.y;
    const int iB  = ks * 128;

    const ushort_t* wqk = wq + (size_t)ks * 65536;

    #pragma unroll
    for (int c = 0; c < 8; c++) {
        const int ll = wv * 8 + c;                   // 0..31
        const int il = ll * 4 + (ln >> 4);           // 0..127
        const int chunk = ln & 15;
        const int rowst = (chunk ^ ((il & 3) << 1)) * 8;   // inverse swizzle
        gload_lds16(ht + (size_t)(iB + il) * M_ + m0 + rowst,
                    lds + ll * 1024 + (ln & 15) * 16 + (ln >> 4) * 256);
    }
    gload_lds16(wqk + (size_t)wv * 512 + ln * 8,
                lds + 32768 + wv * 1024 + ln * 16);
    gload_lds16(wqk + (size_t)(4 + wv) * 512 + ln * 8,
                lds + 32768 + (4 + wv) * 1024 + ln * 16);
    short8 wA0 = *(const short8*)(wqk + (size_t)(8 + wv) * 512 + ln * 8);
    short8 wA1 = *(const short8*)(wqk + (size_t)(12 + wv) * 512 + ln * 8);
    short8 wB0 = *(const short8*)(wqk + (size_t)(16 + wv) * 512 + ln * 8);
    short8 wB1 = *(const short8*)(wqk + (size_t)(20 + wv) * 512 + ln * 8);
    __syncthreads();

    const int hb0 = g * 256 + ((wv * 64 + lr * 2) ^ (g << 5));
    const int hb1 = g * 256 + ((wv * 64 + 32 + lr * 2) ^ (g << 5));

    f32x4 acc[2][4] = {};

    #pragma unroll 4
    for (int p = 0; p < 16; ++p) {
        char* rb = lds + 32768 + (p & 1) * 8192;
        short8 bfr[8];
        #pragma unroll
        for (int f = 0; f < 8; f++)
            bfr[f] = *(short8*)(rb + f * 1024 + ln * 16);

        if (p < 15) {
            char* wbuf = lds + 32768 + ((p + 1) & 1) * 8192;
            *(short8*)(wbuf + wv * 1024 + ln * 16)       = wA0;
            *(short8*)(wbuf + (4 + wv) * 1024 + ln * 16) = wA1;
        }
        wA0 = wB0; wA1 = wB1;
        if (p < 13) {
            wB0 = *(const short8*)(wqk + (size_t)((p + 3) * 8 + wv) * 512 + ln * 8);
            wB1 = *(const short8*)(wqk + (size_t)((p + 3) * 8 + 4 + wv) * 512 + ln * 8);
        }

        const int itA = 2 * p, itB = 2 * p + 1;
        short8 a0, a1, a2, a3;
        eval_bases2(b2f(*(const ushort_t*)(lds + hb0 + itA * 1024)),
                    b2f(*(const ushort_t*)(lds + hb1 + itA * 1024)), a0, a1);
        eval_bases2(b2f(*(const ushort_t*)(lds + hb0 + itB * 1024)),
                    b2f(*(const ushort_t*)(lds + hb1 + itB * 1024)), a2, a3);

        acc[0][0] = __builtin_amdgcn_mfma_f32_16x16x32_bf16(a0, bfr[0], acc[0][0], 0, 0, 0);
        acc[0][1] = __builtin_amdgcn_mfma_f32_16x16x32_bf16(a0, bfr[1], acc[0][1], 0, 0, 0);
        acc[0][2] = __builtin_amdgcn_mfma_f32_16x16x32_bf16(a0, bfr[2], acc[0][2], 0, 0, 0);
        acc[0][3] = __builtin_amdgcn_mfma_f32_16x16x32_bf16(a0, bfr[3], acc[0][3], 0, 0, 0);
        acc[1][0] = __builtin_amdgcn_mfma_f32_16x16x32_bf16(a1, bfr[0], acc[1][0], 0, 0, 0);
        acc[1][1] = __builtin_amdgcn_mfma_f32_16x16x32_bf16(a1, bfr[1], acc[1][1], 0, 0, 0);
        acc[1][2] = __builtin_amdgcn_mfma_f32_16x16x32_bf16(a1, bfr[2], acc[1][2], 0, 0, 0);
        acc[1][3] = __builtin_amdgcn_mfma_f32_16x16x32_bf16(a1, bfr[3], acc[1][3], 0, 0, 0);
        acc[0][0] = __builtin_amdgcn_mfma_f32_16x16x32_bf16(a2, bfr[4], acc[0][0], 0, 0, 0);
        acc[0][1] = __builtin_amdgcn_mfma_f32_16x16x32_bf16(a2, bfr[5], acc[0][1], 0, 0, 0);
        acc[0][2] = __builtin_amdgcn_mfma_f32_16x16x32_bf16(a2, bfr[6], acc[0][2], 0, 0, 0);
        acc[0][3] = __builtin_amdgcn_mfma_f32_16x16x32_bf16(a2, bfr[7], acc[0][3], 0, 0, 0);
        acc[1][0] = __builtin_amdgcn_mfma_f32_16x16x32_bf16(a3, bfr[4], acc[1][0], 0, 0, 0);
        acc[1][1] = __builtin_amdgcn_mfma_f32_16x16x32_bf16(a3, bfr[5], acc[1][1], 0, 0, 0);
        acc[1][2] = __builtin_amdgcn_mfma_f32_16x16x32_bf16(a3, bfr[6], acc[1][2], 0, 0, 0);
        acc[1][3] = __builtin_amdgcn_mfma_f32_16x16x32_bf16(a3, bfr[7], acc[1][3], 0, 0, 0);

        __syncthreads();
    }

    #pragma unroll
    for (int rt = 0; rt < 2; rt++) {
        #pragma unroll
        for (int ct = 0; ct < 4; ct++) {
            const int o = ct * 16 + lr;
            #pragma unroll
            for (int q = 0; q < 4; q++) {
                const size_t row = (size_t)(m0 + wv * 32 + rt * 16 + g * 4 + q);
                kanp[(size_t)ks * (M_ * 64) + row * 64 + o] = (_Float16)acc[rt][ct][q];
            }
        }
    }
}

// ---------------------------------------------------------------------------
// reduce_kan: kanr[m][o] bf16 = sum_ks kanp_fp16[ks][m][o]
// ---------------------------------------------------------------------------
__global__ __launch_bounds__(256) void reduce_kan(
    const _Float16* __restrict__ kanp, ushort_t* __restrict__ kanr)
{
    const int e8 = blockIdx.x * 256 + threadIdx.x;   // 131072 threads
    const size_t base = (size_t)e8 * 8;
    float s[8] = {};
    #pragma unroll
    for (int p = 0; p < KS_; p++) {
        const halfx8 v = *(const halfx8*)(kanp + (size_t)p * (M_ * 64) + base);
        #pragma unroll
        for (int j = 0; j < 8; j++) s[j] += (float)v[j];
    }
    float4 s0 = make_float4(s[0], s[1], s[2], s[3]);
    float4 s1 = make_float4(s[4], s[5], s[6], s[7]);
    ulongx2 outv;
    outv.x = pack4(s0);
    outv.y = pack4(s1);
    *(ulongx2*)(kanr + base) = outv;
}

// ---------------------------------------------------------------------------
// final_v2: out = kanr @ Wf^T + bf, MFMA, float4 stores.
// ---------------------------------------------------------------------------
__global__ __launch_bounds__(256) void final_v2(
    const ushort_t* __restrict__ kanr,
    const ushort_t* __restrict__ wfq,
    const float* __restrict__ bf,
    float* __restrict__ out)
{
    const int tid = threadIdx.x;
    const int wv  = tid >> 6;
    const int ln  = tid & 63;
    const int lr  = ln & 15;
    const int hi  = ln >> 4;
    const int wvm = wv >> 1;
    const int wvt = wv & 1;
    const int mb  = blockIdx.x;
    const int tb  = blockIdx.y;

    f32x4 acc[4][4] = {};

    #pragma unroll
    for (int s = 0; s < 2; s++) {
        short8 afr[4], bfr[4];
        #pragma unroll
        for (int rt = 0; rt < 4; rt++) {
            const size_t idx = ((size_t)(((tb * 2 + wvt) * 2 + s) * 4 + rt)) * 64 + ln;
            afr[rt] = ((const short8*)wfq)[idx];
        }
        #pragma unroll
        for (int ct = 0; ct < 4; ct++) {
            const int m = mb * 128 + wvm * 64 + ct * 16 + lr;
            bfr[ct] = *(const short8*)(kanr + (size_t)m * 64 + s * 32 + hi * 8);
        }
        #pragma unroll
        for (int rt = 0; rt < 4; rt++)
            #pragma unroll
            for (int ct = 0; ct < 4; ct++)
                acc[rt][ct] = __builtin_amdgcn_mfma_f32_16x16x32_bf16(
                    afr[rt], bfr[ct], acc[rt][ct], 0, 0, 0);
    }

    #pragma unroll
    for (int rt = 0; rt < 4; rt++) {
        const int tf0 = tb * 128 + wvt * 64 + rt * 16 + hi * 4;
        const float4 b4 = *(const float4*)&bf[tf0];
        const int t  = tf0 >> 3;
        const int f0 = tf0 & 7;
        #pragma unroll
        for (int ct = 0; ct < 4; ct++) {
            const int m = mb * 128 + wvm * 64 + ct * 16 + lr;
            const int bb = m >> 9;
            const int n  = m & 511;
            const f32x4 v = acc[rt][ct];
            float4 o4 = make_float4(v[0] + b4.x, v[1] + b4.y, v[2] + b4.z, v[3] + b4.w);
            *(float4*)&out[(size_t)bb * (T_ * N_ * F_)
                           + (size_t)t * (N_ * F_)
                           + (size_t)n * F_ + f0] = o4;
        }
    }
}

// ---------------------------------------------------------------------------
extern "C" void kernel_launch(void* const* d_in, const int* in_sizes, int n_in,
                              void* d_out, int out_size, void* d_ws, size_t ws_size,
                              hipStream_t stream)
{
    const float* X      = (const float*)d_in[0];
    const float* Y      = (const float*)d_in[1];
    const float* Wx     = (const float*)d_in[2];
    const float* bx     = (const float*)d_in[3];
    const float* Wy     = (const float*)d_in[4];
    const float* by     = (const float*)d_in[5];
    const float* base_w = (const float*)d_in[6];
    const float* spline_w = (const float*)d_in[7];
    const float* spline_scaler = (const float*)d_in[8];
    const float* Wf     = (const float*)d_in[9];
    const float* bf     = (const float*)d_in[10];

    float* out = (float*)d_out;
    ushort_t* ht   = (ushort_t*)((char*)d_ws + HT_B);
    ushort_t* wq   = (ushort_t*)((char*)d_ws + WQ_B);
    ushort_t* wb   = (ushort_t*)((char*)d_ws + WB_B);
    _Float16* kanp = (_Float16*)((char*)d_ws + SH_B);
    ushort_t* kanr = (ushort_t*)((char*)d_ws + KANR_B);
    ushort_t* wfq  = (ushort_t*)((char*)d_ws + WFQ_B);

    pack_wq<<<2048, 256, 0, stream>>>(base_w, spline_w, spline_scaler, wq);
    pack_wb2<<<3072, 256, 0, stream>>>(Wx, Wy, wb);
    pack_wfq<<<192, 256, 0, stream>>>(Wf, wfq);

    gemm_tanh_v10<<<1024, 512, 0, stream>>>(X, Y, wb, bx, by, ht);

    kan_v10b<<<dim3(M_ / 128, KS_), 256, 0, stream>>>(ht, wq, kanp);
    reduce_kan<<<512, 256, 0, stream>>>(kanp, kanr);
    final_v2<<<dim3(128, 6), 256, 0, stream>>>(kanr, wfq, bf, out);
}